// Round 1
// 226.041 us; speedup vs baseline: 1.2256x; 1.2256x over previous
//
#include <hip/hip_runtime.h>
#include <math.h>

#define L 4096
#define LOG2E_O8 0.18033688011112042f  // 0.125 * log2(e): folds softmax exp->exp2

typedef float f32x16 __attribute__((ext_vector_type(16)));
typedef __bf16 bf16x8 __attribute__((ext_vector_type(8)));

static __device__ __forceinline__ float fast_exp2(float x) {
    return __builtin_amdgcn_exp2f(x);  // v_exp_f32: D = 2^S0
}
static __device__ __forceinline__ unsigned short f2bfu(float f) {
    unsigned int u = __builtin_bit_cast(unsigned int, f);
    u += 0x7fffu + ((u >> 16) & 1u);
    return (unsigned short)(u >> 16);
}
// v_cvt_pk_bf16_f32: dst.lo = bf16(a), dst.hi = bf16(b) — 1 instr vs ~7 for the bit-trick
static __device__ __forceinline__ unsigned int cvtpk(float a, float b) {
    unsigned int r;
    asm("v_cvt_pk_bf16_f32 %0, %1, %2" : "=v"(r) : "v"(a), "v"(b));
    return r;
}
// v_permlane32_swap_b32: a.hi(lanes 32-63) <-> b.lo(lanes 0-31); both results usable
static __device__ __forceinline__ void pl32swap(unsigned int& a, unsigned int& b) {
    auto r = __builtin_amdgcn_permlane32_swap(a, b, false, false);
    a = r[0];
    b = r[1];
}
static __device__ __forceinline__ bf16x8 ld_frag_g(const unsigned short* p) {
    uint4 v = *(const uint4*)p;
    return __builtin_bit_cast(bf16x8, v);
}
static __device__ __forceinline__ bf16x8 ld_frag_s(const unsigned short* p) {
    uint4 v = *(const uint4*)p;  // ds_read_b128
    return __builtin_bit_cast(bf16x8, v);
}

// ---------------- GroupNorm statistics, pass 1: 512 blocks (16 parts per (b,g)) ----------------
// Old single-pass version used grid=32 on a 256-CU chip: latency-bound, ~60us. Split it.
__global__ __launch_bounds__(256) void gn_stats_part_kernel(const float* __restrict__ x,
                                                            float2* __restrict__ part) {
    const int blk = blockIdx.x;  // bg*16 + p ; each block sums 8192 floats (contiguous 32KB)
    const float4* p = (const float4*)(x + (size_t)blk * 8192);
    float sum = 0.f, sq = 0.f;
    for (int i = threadIdx.x; i < 2048; i += 256) {
        float4 v = p[i];
        sum += (v.x + v.y) + (v.z + v.w);
        sq  += (v.x * v.x + v.y * v.y) + (v.z * v.z + v.w * v.w);
    }
#pragma unroll
    for (int off = 1; off < 64; off <<= 1) {
        sum += __shfl_xor(sum, off);
        sq  += __shfl_xor(sq, off);
    }
    __shared__ float red[8];
    const int t = threadIdx.x;
    if ((t & 63) == 0) { red[(t >> 6) * 2] = sum; red[(t >> 6) * 2 + 1] = sq; }
    __syncthreads();
    if (t == 0) {
        float s = red[0] + red[2] + red[4] + red[6];
        float q = red[1] + red[3] + red[5] + red[7];
        part[blk] = make_float2(s, q);
    }
}

// ---------------- GroupNorm statistics, pass 2: finalize 32 (b,g) groups ----------------
__global__ __launch_bounds__(64) void gn_stats_final_kernel(const float2* __restrict__ part,
                                                            float2* __restrict__ stats) {
    const int bg = threadIdx.x;
    if (bg < 32) {
        float s = 0.f, q = 0.f;
#pragma unroll
        for (int i = 0; i < 16; ++i) {
            float2 v = part[bg * 16 + i];
            s += v.x; q += v.y;
        }
        const float inv_n = 1.0f / (32.0f * L);
        float mean = s * inv_n;
        float var = q * inv_n - mean * mean;
        stats[bg] = make_float2(mean, rsqrtf(var + 1e-5f));
    }
}

// ---------------- Weight fp32 -> bf16 (row-major kept) ----------------
__global__ __launch_bounds__(256) void wcvt_kernel(const float* __restrict__ qkv_w,
                                                   const float* __restrict__ proj_w,
                                                   unsigned short* __restrict__ Wqb,
                                                   unsigned short* __restrict__ Wpb) {
    const int i4 = (blockIdx.x * 256 + threadIdx.x) * 4;
    const float* src;
    unsigned short* dst;
    if (i4 < 196608) { src = qkv_w + i4; dst = Wqb + i4; }
    else             { src = proj_w + (i4 - 196608); dst = Wpb + (i4 - 196608); }
    float4 v = *(const float4*)src;
    ushort4 o;
    o.x = f2bfu(v.x); o.y = f2bfu(v.y); o.z = f2bfu(v.z); o.w = f2bfu(v.w);
    *(ushort4*)dst = o;
}

// ---------------- GN-apply + transpose: x[b][c][l] fp32 -> xnT[b][l][c] bf16 ----------------
__global__ __launch_bounds__(256) void gn_apply_kernel(const float* __restrict__ x,
                                                       const float* __restrict__ gamma,
                                                       const float* __restrict__ beta,
                                                       const float2* __restrict__ stats,
                                                       unsigned short* __restrict__ xnT) {
    __shared__ float tile[64][68];
    const int t = threadIdx.x;
    const int b = blockIdx.z, c0 = blockIdx.y * 64, l0 = blockIdx.x * 64;
    const int lc = (t & 15) * 4, cr = t >> 4;
#pragma unroll
    for (int p = 0; p < 4; ++p) {
        const int c = c0 + cr + p * 16;
        const float2 st = stats[b * 8 + (c >> 5)];
        const float g = gamma[c] * st.y;
        const float be = beta[c] - st.x * g;
        float4 v = *(const float4*)&x[((size_t)b * 256 + c) * L + l0 + lc];
        float4 o;
        o.x = v.x * g + be; o.y = v.y * g + be; o.z = v.z * g + be; o.w = v.w * g + be;
        *(float4*)&tile[cr + p * 16][lc] = o;
    }
    __syncthreads();
    const int lr = t >> 2, cc = (t & 3) * 16;
    unsigned short* dst = &xnT[((size_t)b * L + l0 + lr) * 256 + c0 + cc];
#pragma unroll
    for (int g4 = 0; g4 < 4; ++g4) {
        ushort4 o4;
        o4.x = f2bfu(tile[cc + g4 * 4 + 0][lr]);
        o4.y = f2bfu(tile[cc + g4 * 4 + 1][lr]);
        o4.z = f2bfu(tile[cc + g4 * 4 + 2][lr]);
        o4.w = f2bfu(tile[cc + g4 * 4 + 3][lr]);
        *(ushort4*)&dst[g4 * 4] = o4;
    }
}

// ---------------- QKV GEMM (MFMA, no LDS): T[n][m] = sum_k xnT[n][k] * Wq[m][k] ----------------
// Q: [b][h][L][64] bf16 (pre-scaled LOG2E_O8), K: [b][h][L][64], V: [b][h][64][L]
__global__ __launch_bounds__(256) void qkv_gemm_kernel(
        const unsigned short* __restrict__ xnT,
        const unsigned short* __restrict__ Wq,
        const float* __restrict__ bias,
        unsigned short* __restrict__ Qb,
        unsigned short* __restrict__ Kb,
        unsigned short* __restrict__ Vb) {
    const int t = threadIdx.x, lane = t & 63, w = t >> 6;
    const int l5 = lane >> 5, l31 = lane & 31;
    const int wn = w & 1, wm = w >> 1;
    const int n0 = blockIdx.x * 128 + wn * 64;
    const int m0 = blockIdx.y * 128 + wm * 64;
    const int b = blockIdx.z;
    const unsigned short* ap = xnT + ((size_t)b * L + n0 + l31) * 256 + l5 * 8;
    const unsigned short* bp = Wq + (size_t)(m0 + l31) * 256 + l5 * 8;
    f32x16 acc[2][2];
#pragma unroll
    for (int i = 0; i < 2; ++i)
#pragma unroll
        for (int j = 0; j < 2; ++j)
#pragma unroll
            for (int r = 0; r < 16; ++r) acc[i][j][r] = 0.f;
#pragma unroll
    for (int k0 = 0; k0 < 256; k0 += 16) {
        bf16x8 a0 = ld_frag_g(ap + k0);
        bf16x8 a1 = ld_frag_g(ap + 32 * 256 + k0);
        bf16x8 b0 = ld_frag_g(bp + k0);
        bf16x8 b1 = ld_frag_g(bp + 32 * 256 + k0);
        acc[0][0] = __builtin_amdgcn_mfma_f32_32x32x16_bf16(a0, b0, acc[0][0], 0, 0, 0);
        acc[0][1] = __builtin_amdgcn_mfma_f32_32x32x16_bf16(a0, b1, acc[0][1], 0, 0, 0);
        acc[1][0] = __builtin_amdgcn_mfma_f32_32x32x16_bf16(a1, b0, acc[1][0], 0, 0, 0);
        acc[1][1] = __builtin_amdgcn_mfma_f32_32x32x16_bf16(a1, b1, acc[1][1], 0, 0, 0);
    }
    const int sec = m0 >> 8;                       // 0=Q, 1=K, 2=V (uniform per wave)
    const size_t bh = (size_t)(b * 4 + ((m0 >> 6) & 3));
#pragma unroll
    for (int j = 0; j < 2; ++j) {
        const int m = m0 + j * 32 + l31;
        const int d = m & 63;
        const float bi = bias[m];
        if (sec < 2) {
            unsigned short* dst = (sec ? Kb : Qb) + bh * L * 64 + d;
            const float sc = (sec == 0) ? LOG2E_O8 : 1.0f;
#pragma unroll
            for (int i = 0; i < 2; ++i)
#pragma unroll
                for (int r = 0; r < 16; ++r) {
                    const int n = n0 + i * 32 + (r & 3) + 8 * (r >> 2) + 4 * l5;
                    dst[(size_t)n * 64] = f2bfu((acc[i][j][r] + bi) * sc);
                }
        } else {
            unsigned short* dst = Vb + (bh * 64 + d) * L;
#pragma unroll
            for (int i = 0; i < 2; ++i)
#pragma unroll
                for (int g = 0; g < 4; ++g) {
                    const int n = n0 + i * 32 + 8 * g + 4 * l5;
                    ushort4 st;
                    st.x = f2bfu(acc[i][j][4 * g + 0] + bi);
                    st.y = f2bfu(acc[i][j][4 * g + 1] + bi);
                    st.z = f2bfu(acc[i][j][4 * g + 2] + bi);
                    st.w = f2bfu(acc[i][j][4 * g + 3] + bi);
                    *(ushort4*)&dst[n] = st;
                }
        }
    }
}

// ---------------- MFMA flash attention: LDS-shared K/V + 2 blocks/CU for TLP ----------------
// R12 (LDS staging) broke the TA bottleneck: 247->154us. Grid 512, launch_bounds(256,2)
// -> 2 blocks/CU = 2 waves/SIMD. This round (T12): the P->bf16 repack path was the VALU
// hog (8 manual pk2bf ~7 ops each + 8 ds_bpermute shfls + 16 cndmask). Replaced with
// 8x v_cvt_pk_bf16_f32 + 4x v_permlane32_swap_b32 (swap A.hi<->B.lo; pairing regs 4 apart
// makes both outputs land exactly in the B-fragment k-slots; verified per-lane against
// C-layout k=(r&3)+8*(r>>2)+4*l5).
__global__ __launch_bounds__(256, 2) void attn_kernel(
        const unsigned short* __restrict__ Qb,
        const unsigned short* __restrict__ Kb,
        const unsigned short* __restrict__ Vb,
        unsigned short* __restrict__ aoT) {
    const int t = threadIdx.x;
    const int lane = t & 63, w = t >> 6;
    const int l5 = lane >> 5, l31 = lane & 31;
    const int n = blockIdx.x;
    const int bh_i = n & 15;                         // XCD = n%8 = bh%8
    const int qt = n >> 4;                           // 0..31
    const int b = bh_i >> 2, h = bh_i & 3;
    const int q0 = qt * 128 + w * 32;                // wave owns 32 q
    const size_t bh = (size_t)bh_i;

    __shared__ alignas(16) unsigned short Kt[2][32][72];  // 32 k-rows x 64 d (+4 pad)
    __shared__ alignas(16) unsigned short Vt[2][64][40];  // 64 d-rows x 32 k (+4 pad)

    const unsigned short* qp = Qb + (bh * L + q0 + l31) * 64 + l5 * 8;
    bf16x8 qf[4];
#pragma unroll
    for (int dc = 0; dc < 4; ++dc) qf[dc] = ld_frag_g(qp + dc * 16);

    // staging addresses (coalesced 16B/lane)
    const int kr = t >> 3, kq = t & 7;   // K: row 0..31, 16B piece 0..7
    const int vd = t >> 2, vp = t & 3;   // V: row 0..63, 16B piece 0..3
    const unsigned short* kgsrc = Kb + bh * L * 64 + kr * 64 + kq * 8;
    const unsigned short* vgsrc = Vb + (bh * 64 + vd) * L + vp * 8;

    f32x16 o0, o1;
#pragma unroll
    for (int r = 0; r < 16; ++r) { o0[r] = 0.f; o1[r] = 0.f; }
    float4 ls = make_float4(0.f, 0.f, 0.f, 0.f);

    // prestage chunk 0
    {
        uint4 kv = *(const uint4*)kgsrc;
        uint4 vv = *(const uint4*)vgsrc;
        *(uint4*)&Kt[0][kr][kq * 8] = kv;
        *(uint4*)&Vt[0][vd][vp * 8] = vv;
    }
    __syncthreads();

    for (int kc = 0; kc < 128; ++kc) {
        const int buf = kc & 1;
        uint4 knx, vnx;
        if (kc < 127) {  // issue next-chunk global loads early; consumed at bottom
            knx = *(const uint4*)(kgsrc + (size_t)(kc + 1) * 2048);
            vnx = *(const uint4*)(vgsrc + (kc + 1) * 32);
        }
        // fragments from LDS
        bf16x8 kf[4], vf[2][2];
#pragma unroll
        for (int dc = 0; dc < 4; ++dc)
            kf[dc] = ld_frag_s(&Kt[buf][l31][dc * 16 + l5 * 8]);
#pragma unroll
        for (int dh = 0; dh < 2; ++dh)
#pragma unroll
            for (int h16 = 0; h16 < 2; ++h16)
                vf[dh][h16] = ld_frag_s(&Vt[buf][dh * 32 + l31][h16 * 16 + l5 * 8]);
        f32x16 s;
#pragma unroll
        for (int r = 0; r < 16; ++r) s[r] = 0.f;
#pragma unroll
        for (int dc = 0; dc < 4; ++dc)
            s = __builtin_amdgcn_mfma_f32_32x32x16_bf16(kf[dc], qf[dc], s, 0, 0, 0);
        // no-shift exp2 softmax (element-wise only)
#pragma unroll
        for (int r = 0; r < 16; ++r) s[r] = fast_exp2(s[r]);
#pragma unroll
        for (int g = 0; g < 4; ++g) {
            ls.x += s[4 * g + 0];
            ls.y += s[4 * g + 1];
            ls.z += s[4 * g + 2];
            ls.w += s[4 * g + 3];
        }
        // T12: pack to bf16 in-register, redistribute halves with permlane32_swap.
        unsigned int w0 = cvtpk(s[0],  s[1]);   // l5=0:(k0,k1)   l5=1:(k4,k5)
        unsigned int w1 = cvtpk(s[2],  s[3]);   // l5=0:(k2,k3)   l5=1:(k6,k7)
        unsigned int w2 = cvtpk(s[4],  s[5]);   // l5=0:(k8,k9)   l5=1:(k12,k13)
        unsigned int w3 = cvtpk(s[6],  s[7]);   // l5=0:(k10,k11) l5=1:(k14,k15)
        unsigned int w4 = cvtpk(s[8],  s[9]);
        unsigned int w5 = cvtpk(s[10], s[11]);
        unsigned int w6 = cvtpk(s[12], s[13]);
        unsigned int w7 = cvtpk(s[14], s[15]);
        pl32swap(w0, w2);  // -> w0: word0 of pb0 (both halves), w2: word2
        pl32swap(w1, w3);  // -> w1: word1,                      w3: word3
        pl32swap(w4, w6);  // pb1 words 0,2
        pl32swap(w5, w7);  // pb1 words 1,3
        int4 p0v, p1v;
        p0v.x = (int)w0; p0v.y = (int)w1; p0v.z = (int)w2; p0v.w = (int)w3;
        p1v.x = (int)w4; p1v.y = (int)w5; p1v.z = (int)w6; p1v.w = (int)w7;
        bf16x8 pb0 = __builtin_bit_cast(bf16x8, p0v);
        bf16x8 pb1 = __builtin_bit_cast(bf16x8, p1v);
        o0 = __builtin_amdgcn_mfma_f32_32x32x16_bf16(vf[0][0], pb0, o0, 0, 0, 0);
        o0 = __builtin_amdgcn_mfma_f32_32x32x16_bf16(vf[0][1], pb1, o0, 0, 0, 0);
        o1 = __builtin_amdgcn_mfma_f32_32x32x16_bf16(vf[1][0], pb0, o1, 0, 0, 0);
        o1 = __builtin_amdgcn_mfma_f32_32x32x16_bf16(vf[1][1], pb1, o1, 0, 0, 0);
        if (kc < 127) {
            *(uint4*)&Kt[buf ^ 1][kr][kq * 8] = knx;
            *(uint4*)&Vt[buf ^ 1][vd][vp * 8] = vnx;
        }
        __syncthreads();
    }
    float lrun = (ls.x + ls.y) + (ls.z + ls.w);
    lrun += __shfl_xor(lrun, 32);
    const float inv = 1.f / lrun;
    unsigned short* op = aoT + ((size_t)b * L + q0 + l31) * 256 + h * 64 + 4 * l5;
#pragma unroll
    for (int g = 0; g < 4; ++g) {
        uint2 st;
        st.x = cvtpk(o0[4 * g + 0] * inv, o0[4 * g + 1] * inv);
        st.y = cvtpk(o0[4 * g + 2] * inv, o0[4 * g + 3] * inv);
        *(uint2*)&op[8 * g] = st;
        uint2 st2;
        st2.x = cvtpk(o1[4 * g + 0] * inv, o1[4 * g + 1] * inv);
        st2.y = cvtpk(o1[4 * g + 2] * inv, o1[4 * g + 3] * inv);
        *(uint2*)&op[32 + 8 * g] = st2;
    }
}

// ---------------- Proj GEMM (MFMA) + bias + GN residual, fp32 out ----------------
__global__ __launch_bounds__(256) void proj_gemm_kernel(
        const unsigned short* __restrict__ aoT,
        const unsigned short* __restrict__ Wp,
        const float* __restrict__ bias,
        const float* __restrict__ x,
        const float* __restrict__ gamma,
        const float* __restrict__ beta,
        const float2* __restrict__ stats,
        float* __restrict__ out) {
    const int t = threadIdx.x, lane = t & 63, w = t >> 6;
    const int l5 = lane >> 5, l31 = lane & 31;
    const int wn = w & 1, wm = w >> 1;
    const int n0 = blockIdx.x * 64 + wn * 32;
    const int m0 = blockIdx.y * 128 + wm * 64;
    const int b = blockIdx.z;
    const unsigned short* ap = aoT + ((size_t)b * L + n0 + l31) * 256 + l5 * 8;
    const unsigned short* bp = Wp + (size_t)(m0 + l31) * 256 + l5 * 8;
    f32x16 acc[2];
#pragma unroll
    for (int j = 0; j < 2; ++j)
#pragma unroll
        for (int r = 0; r < 16; ++r) acc[j][r] = 0.f;
#pragma unroll
    for (int k0 = 0; k0 < 256; k0 += 16) {
        bf16x8 a  = ld_frag_g(ap + k0);
        bf16x8 b0 = ld_frag_g(bp + k0);
        bf16x8 b1 = ld_frag_g(bp + 32 * 256 + k0);
        acc[0] = __builtin_amdgcn_mfma_f32_32x32x16_bf16(a, b0, acc[0], 0, 0, 0);
        acc[1] = __builtin_amdgcn_mfma_f32_32x32x16_bf16(a, b1, acc[1], 0, 0, 0);
    }
#pragma unroll
    for (int j = 0; j < 2; ++j) {
        const int co = m0 + j * 32 + l31;
        const float2 st = stats[b * 8 + (co >> 5)];
        const float g = gamma[co] * st.y;
        const float be = beta[co] - st.x * g + bias[co];
        const float* xr = &x[((size_t)b * 256 + co) * L];
        float* orow = &out[((size_t)b * 256 + co) * L];
#pragma unroll
        for (int q = 0; q < 4; ++q) {
            const int n = n0 + 8 * q + 4 * l5;
            float4 xv = *(const float4*)&xr[n];
            float4 ov;
            ov.x = acc[j][4 * q + 0] + (xv.x * g + be);
            ov.y = acc[j][4 * q + 1] + (xv.y * g + be);
            ov.z = acc[j][4 * q + 2] + (xv.z * g + be);
            ov.w = acc[j][4 * q + 3] + (xv.w * g + be);
            *(float4*)&orow[n] = ov;
        }
    }
}

extern "C" void kernel_launch(void* const* d_in, const int* in_sizes, int n_in,
                              void* d_out, int out_size, void* d_ws, size_t ws_size,
                              hipStream_t stream) {
    const float* x      = (const float*)d_in[0];
    const float* qkv_w  = (const float*)d_in[1];
    const float* qkv_b  = (const float*)d_in[2];
    const float* proj_w = (const float*)d_in[3];
    const float* proj_b = (const float*)d_in[4];
    const float* gamma  = (const float*)d_in[5];
    const float* beta   = (const float*)d_in[6];
    float* out = (float*)d_out;

    char* ws = (char*)d_ws;
    float2* stats       = (float2*)ws;                                   // 256 B
    unsigned short* Wqb = (unsigned short*)(ws + 512);                   // 384 KiB
    unsigned short* Wpb = (unsigned short*)(ws + 512 + 393216);          // 128 KiB
    unsigned short* xnT = (unsigned short*)(ws + 524800);                // 8 MiB
    unsigned short* Qb  = (unsigned short*)(ws + 524800 + 8388608);      // 8 MiB
    unsigned short* Kb  = Qb + (size_t)16 * L * 64;                      // 8 MiB
    unsigned short* Vb  = Kb + (size_t)16 * L * 64;                      // 8 MiB
    unsigned short* aoT = Vb + (size_t)16 * L * 64;                      // 8 MiB
    // stats partials live at the head of the xnT region: consumed by gn_stats_final
    // BEFORE gn_apply writes xnT (stream-ordered) — no extra workspace needed.
    float2* spart       = (float2*)(ws + 524800);                        // 4 KiB

    gn_stats_part_kernel<<<dim3(512), dim3(256), 0, stream>>>(x, spart);
    gn_stats_final_kernel<<<dim3(1), dim3(64), 0, stream>>>(spart, stats);
    wcvt_kernel<<<dim3(256), dim3(256), 0, stream>>>(qkv_w, proj_w, Wqb, Wpb);
    gn_apply_kernel<<<dim3(64, 4, 4), dim3(256), 0, stream>>>(x, gamma, beta, stats, xnT);
    qkv_gemm_kernel<<<dim3(32, 6, 4), dim3(256), 0, stream>>>(xnT, Wqb, qkv_b, Qb, Kb, Vb);
    attn_kernel<<<dim3(512), dim3(256), 0, stream>>>(Qb, Kb, Vb, aoT);
    proj_gemm_kernel<<<dim3(64, 2, 4), dim3(256), 0, stream>>>(aoT, Wpb, proj_b, x, gamma, beta, stats, out);
}

// Round 2
// 221.295 us; speedup vs baseline: 1.2519x; 1.0214x over previous
//
#include <hip/hip_runtime.h>
#include <math.h>

#define L 4096
#define LOG2E_O8 0.18033688011112042f  // 0.125 * log2(e): folds softmax exp->exp2

typedef float f32x16 __attribute__((ext_vector_type(16)));
typedef __bf16 bf16x8 __attribute__((ext_vector_type(8)));

static __device__ __forceinline__ float fast_exp2(float x) {
    return __builtin_amdgcn_exp2f(x);  // v_exp_f32: D = 2^S0
}
static __device__ __forceinline__ unsigned short f2bfu(float f) {
    unsigned int u = __builtin_bit_cast(unsigned int, f);
    u += 0x7fffu + ((u >> 16) & 1u);
    return (unsigned short)(u >> 16);
}
// v_cvt_pk_bf16_f32: dst.lo = bf16(a), dst.hi = bf16(b) — 1 instr vs ~7 for the bit-trick
static __device__ __forceinline__ unsigned int cvtpk(float a, float b) {
    unsigned int r;
    asm("v_cvt_pk_bf16_f32 %0, %1, %2" : "=v"(r) : "v"(a), "v"(b));
    return r;
}
// v_permlane32_swap_b32: a.hi(lanes 32-63) <-> b.lo(lanes 0-31); both results usable
static __device__ __forceinline__ void pl32swap(unsigned int& a, unsigned int& b) {
    auto r = __builtin_amdgcn_permlane32_swap(a, b, false, false);
    a = r[0];
    b = r[1];
}
static __device__ __forceinline__ bf16x8 ld_frag_g(const unsigned short* p) {
    uint4 v = *(const uint4*)p;
    return __builtin_bit_cast(bf16x8, v);
}
static __device__ __forceinline__ bf16x8 ld_frag_s(const unsigned short* p) {
    uint4 v = *(const uint4*)p;  // ds_read_b128
    return __builtin_bit_cast(bf16x8, v);
}

// ---------------- GroupNorm statistics, pass 1: 512 blocks (16 parts per (b,g)) ----------------
__global__ __launch_bounds__(256) void gn_stats_part_kernel(const float* __restrict__ x,
                                                            float2* __restrict__ part) {
    const int blk = blockIdx.x;  // bg*16 + p ; each block sums 8192 floats (contiguous 32KB)
    const float4* p = (const float4*)(x + (size_t)blk * 8192);
    float sum = 0.f, sq = 0.f;
    for (int i = threadIdx.x; i < 2048; i += 256) {
        float4 v = p[i];
        sum += (v.x + v.y) + (v.z + v.w);
        sq  += (v.x * v.x + v.y * v.y) + (v.z * v.z + v.w * v.w);
    }
#pragma unroll
    for (int off = 1; off < 64; off <<= 1) {
        sum += __shfl_xor(sum, off);
        sq  += __shfl_xor(sq, off);
    }
    __shared__ float red[8];
    const int t = threadIdx.x;
    if ((t & 63) == 0) { red[(t >> 6) * 2] = sum; red[(t >> 6) * 2 + 1] = sq; }
    __syncthreads();
    if (t == 0) {
        float s = red[0] + red[2] + red[4] + red[6];
        float q = red[1] + red[3] + red[5] + red[7];
        part[blk] = make_float2(s, q);
    }
}

// ---------------- GroupNorm statistics, pass 2: finalize 32 (b,g) groups ----------------
__global__ __launch_bounds__(64) void gn_stats_final_kernel(const float2* __restrict__ part,
                                                            float2* __restrict__ stats) {
    const int bg = threadIdx.x;
    if (bg < 32) {
        float s = 0.f, q = 0.f;
#pragma unroll
        for (int i = 0; i < 16; ++i) {
            float2 v = part[bg * 16 + i];
            s += v.x; q += v.y;
        }
        const float inv_n = 1.0f / (32.0f * L);
        float mean = s * inv_n;
        float var = q * inv_n - mean * mean;
        stats[bg] = make_float2(mean, rsqrtf(var + 1e-5f));
    }
}

// ---------------- Weight fp32 -> bf16 (row-major kept) ----------------
__global__ __launch_bounds__(256) void wcvt_kernel(const float* __restrict__ qkv_w,
                                                   const float* __restrict__ proj_w,
                                                   unsigned short* __restrict__ Wqb,
                                                   unsigned short* __restrict__ Wpb) {
    const int i4 = (blockIdx.x * 256 + threadIdx.x) * 4;
    const float* src;
    unsigned short* dst;
    if (i4 < 196608) { src = qkv_w + i4; dst = Wqb + i4; }
    else             { src = proj_w + (i4 - 196608); dst = Wpb + (i4 - 196608); }
    float4 v = *(const float4*)src;
    ushort4 o;
    o.x = f2bfu(v.x); o.y = f2bfu(v.y); o.z = f2bfu(v.z); o.w = f2bfu(v.w);
    *(ushort4*)dst = o;
}

// ---------------- GN-apply + transpose: x[b][c][l] fp32 -> xnT[b][l][c] bf16 ----------------
__global__ __launch_bounds__(256) void gn_apply_kernel(const float* __restrict__ x,
                                                       const float* __restrict__ gamma,
                                                       const float* __restrict__ beta,
                                                       const float2* __restrict__ stats,
                                                       unsigned short* __restrict__ xnT) {
    __shared__ float tile[64][68];
    const int t = threadIdx.x;
    const int b = blockIdx.z, c0 = blockIdx.y * 64, l0 = blockIdx.x * 64;
    const int lc = (t & 15) * 4, cr = t >> 4;
#pragma unroll
    for (int p = 0; p < 4; ++p) {
        const int c = c0 + cr + p * 16;
        const float2 st = stats[b * 8 + (c >> 5)];
        const float g = gamma[c] * st.y;
        const float be = beta[c] - st.x * g;
        float4 v = *(const float4*)&x[((size_t)b * 256 + c) * L + l0 + lc];
        float4 o;
        o.x = v.x * g + be; o.y = v.y * g + be; o.z = v.z * g + be; o.w = v.w * g + be;
        *(float4*)&tile[cr + p * 16][lc] = o;
    }
    __syncthreads();
    const int lr = t >> 2, cc = (t & 3) * 16;
    unsigned short* dst = &xnT[((size_t)b * L + l0 + lr) * 256 + c0 + cc];
#pragma unroll
    for (int g4 = 0; g4 < 4; ++g4) {
        ushort4 o4;
        o4.x = f2bfu(tile[cc + g4 * 4 + 0][lr]);
        o4.y = f2bfu(tile[cc + g4 * 4 + 1][lr]);
        o4.z = f2bfu(tile[cc + g4 * 4 + 2][lr]);
        o4.w = f2bfu(tile[cc + g4 * 4 + 3][lr]);
        *(ushort4*)&dst[g4 * 4] = o4;
    }
}

// ---------------- QKV GEMM (MFMA, no LDS): T[n][m] = sum_k xnT[n][k] * Wq[m][k] ----------------
// Q: [b][h][L][64] bf16 (pre-scaled LOG2E_O8), K: [b][h][L][64], V: [b][h][64][L]
__global__ __launch_bounds__(256) void qkv_gemm_kernel(
        const unsigned short* __restrict__ xnT,
        const unsigned short* __restrict__ Wq,
        const float* __restrict__ bias,
        unsigned short* __restrict__ Qb,
        unsigned short* __restrict__ Kb,
        unsigned short* __restrict__ Vb) {
    const int t = threadIdx.x, lane = t & 63, w = t >> 6;
    const int l5 = lane >> 5, l31 = lane & 31;
    const int wn = w & 1, wm = w >> 1;
    const int n0 = blockIdx.x * 128 + wn * 64;
    const int m0 = blockIdx.y * 128 + wm * 64;
    const int b = blockIdx.z;
    const unsigned short* ap = xnT + ((size_t)b * L + n0 + l31) * 256 + l5 * 8;
    const unsigned short* bp = Wq + (size_t)(m0 + l31) * 256 + l5 * 8;
    f32x16 acc[2][2];
#pragma unroll
    for (int i = 0; i < 2; ++i)
#pragma unroll
        for (int j = 0; j < 2; ++j)
#pragma unroll
            for (int r = 0; r < 16; ++r) acc[i][j][r] = 0.f;
#pragma unroll
    for (int k0 = 0; k0 < 256; k0 += 16) {
        bf16x8 a0 = ld_frag_g(ap + k0);
        bf16x8 a1 = ld_frag_g(ap + 32 * 256 + k0);
        bf16x8 b0 = ld_frag_g(bp + k0);
        bf16x8 b1 = ld_frag_g(bp + 32 * 256 + k0);
        acc[0][0] = __builtin_amdgcn_mfma_f32_32x32x16_bf16(a0, b0, acc[0][0], 0, 0, 0);
        acc[0][1] = __builtin_amdgcn_mfma_f32_32x32x16_bf16(a0, b1, acc[0][1], 0, 0, 0);
        acc[1][0] = __builtin_amdgcn_mfma_f32_32x32x16_bf16(a1, b0, acc[1][0], 0, 0, 0);
        acc[1][1] = __builtin_amdgcn_mfma_f32_32x32x16_bf16(a1, b1, acc[1][1], 0, 0, 0);
    }
    const int sec = m0 >> 8;                       // 0=Q, 1=K, 2=V (uniform per wave)
    const size_t bh = (size_t)(b * 4 + ((m0 >> 6) & 3));
#pragma unroll
    for (int j = 0; j < 2; ++j) {
        const int m = m0 + j * 32 + l31;
        const int d = m & 63;
        const float bi = bias[m];
        if (sec < 2) {
            unsigned short* dst = (sec ? Kb : Qb) + bh * L * 64 + d;
            const float sc = (sec == 0) ? LOG2E_O8 : 1.0f;
#pragma unroll
            for (int i = 0; i < 2; ++i)
#pragma unroll
                for (int r = 0; r < 16; ++r) {
                    const int n = n0 + i * 32 + (r & 3) + 8 * (r >> 2) + 4 * l5;
                    dst[(size_t)n * 64] = f2bfu((acc[i][j][r] + bi) * sc);
                }
        } else {
            unsigned short* dst = Vb + (bh * 64 + d) * L;
#pragma unroll
            for (int i = 0; i < 2; ++i)
#pragma unroll
                for (int g = 0; g < 4; ++g) {
                    const int n = n0 + i * 32 + 8 * g + 4 * l5;
                    ushort4 st;
                    st.x = f2bfu(acc[i][j][4 * g + 0] + bi);
                    st.y = f2bfu(acc[i][j][4 * g + 1] + bi);
                    st.z = f2bfu(acc[i][j][4 * g + 2] + bi);
                    st.w = f2bfu(acc[i][j][4 * g + 3] + bi);
                    *(ushort4*)&dst[n] = st;
                }
        }
    }
}

// ---------------- MFMA flash attention, k-split x2 for TLP ----------------
// R1 post-mortem: 2 waves/SIMD (grid-limited) left ~36% of the round in barrier/latency
// stall (MfmaUtil 31, VALUBusy 35). q-dim is exhausted (32 q/wave fixed by MFMA shape),
// so add waves via k-split: each block does a 2048-k half, emits fp32 partial O + l.
// No-max exp2 softmax => partials merge by pure addition (attn_merge_kernel).
// Grid 1024, launch_bounds(256,4) -> 4 blocks/CU = 4 waves/SIMD.
__global__ __launch_bounds__(256, 4) void attn_kernel(
        const unsigned short* __restrict__ Qb,
        const unsigned short* __restrict__ Kb,
        const unsigned short* __restrict__ Vb,
        float* __restrict__ Po,   // [2][16][4096][64] fp32 partial O
        float* __restrict__ Pl) { // [2][16][4096]     fp32 partial l
    const int t = threadIdx.x;
    const int lane = t & 63, w = t >> 6;
    const int l5 = lane >> 5, l31 = lane & 31;
    const int n = blockIdx.x;
    const int bh_i = n & 15;                         // XCD = n%8 = bh%8
    const int r = n >> 4;                            // 0..63
    const int qt = r & 31;                           // q-tile 0..31
    const int kh = r >> 5;                           // k-half 0..1
    const int q0 = qt * 128 + w * 32;                // wave owns 32 q
    const size_t bh = (size_t)bh_i;

    __shared__ alignas(16) unsigned short Kt[2][32][72];  // 32 k-rows x 64 d (+4 pad)
    __shared__ alignas(16) unsigned short Vt[2][64][40];  // 64 d-rows x 32 k (+4 pad)

    const unsigned short* qp = Qb + (bh * L + q0 + l31) * 64 + l5 * 8;
    bf16x8 qf[4];
#pragma unroll
    for (int dc = 0; dc < 4; ++dc) qf[dc] = ld_frag_g(qp + dc * 16);

    // staging addresses (coalesced 16B/lane); base shifted to this block's k-half
    const int kr = t >> 3, kq = t & 7;   // K: row 0..31, 16B piece 0..7
    const int vd = t >> 2, vp = t & 3;   // V: row 0..63, 16B piece 0..3
    const unsigned short* kgsrc = Kb + bh * L * 64 + (size_t)kh * 2048 * 64 + kr * 64 + kq * 8;
    const unsigned short* vgsrc = Vb + (bh * 64 + vd) * L + kh * 2048 + vp * 8;

    f32x16 o0, o1;
#pragma unroll
    for (int r2 = 0; r2 < 16; ++r2) { o0[r2] = 0.f; o1[r2] = 0.f; }
    float4 ls = make_float4(0.f, 0.f, 0.f, 0.f);

    // prestage chunk 0
    {
        uint4 kv = *(const uint4*)kgsrc;
        uint4 vv = *(const uint4*)vgsrc;
        *(uint4*)&Kt[0][kr][kq * 8] = kv;
        *(uint4*)&Vt[0][vd][vp * 8] = vv;
    }
    __syncthreads();

    for (int kc = 0; kc < 64; ++kc) {
        const int buf = kc & 1;
        uint4 knx, vnx;
        if (kc < 63) {  // issue next-chunk global loads early; consumed at bottom
            knx = *(const uint4*)(kgsrc + (size_t)(kc + 1) * 2048);
            vnx = *(const uint4*)(vgsrc + (kc + 1) * 32);
        }
        // fragments from LDS
        bf16x8 kf[4], vf[2][2];
#pragma unroll
        for (int dc = 0; dc < 4; ++dc)
            kf[dc] = ld_frag_s(&Kt[buf][l31][dc * 16 + l5 * 8]);
#pragma unroll
        for (int dh = 0; dh < 2; ++dh)
#pragma unroll
            for (int h16 = 0; h16 < 2; ++h16)
                vf[dh][h16] = ld_frag_s(&Vt[buf][dh * 32 + l31][h16 * 16 + l5 * 8]);
        f32x16 s;
#pragma unroll
        for (int r2 = 0; r2 < 16; ++r2) s[r2] = 0.f;
#pragma unroll
        for (int dc = 0; dc < 4; ++dc)
            s = __builtin_amdgcn_mfma_f32_32x32x16_bf16(kf[dc], qf[dc], s, 0, 0, 0);
        // no-shift exp2 softmax (element-wise only)
#pragma unroll
        for (int r2 = 0; r2 < 16; ++r2) s[r2] = fast_exp2(s[r2]);
#pragma unroll
        for (int g = 0; g < 4; ++g) {
            ls.x += s[4 * g + 0];
            ls.y += s[4 * g + 1];
            ls.z += s[4 * g + 2];
            ls.w += s[4 * g + 3];
        }
        // T12: pack to bf16 in-register, redistribute halves with permlane32_swap.
        unsigned int w0 = cvtpk(s[0],  s[1]);
        unsigned int w1 = cvtpk(s[2],  s[3]);
        unsigned int w2 = cvtpk(s[4],  s[5]);
        unsigned int w3 = cvtpk(s[6],  s[7]);
        unsigned int w4 = cvtpk(s[8],  s[9]);
        unsigned int w5 = cvtpk(s[10], s[11]);
        unsigned int w6 = cvtpk(s[12], s[13]);
        unsigned int w7 = cvtpk(s[14], s[15]);
        pl32swap(w0, w2);
        pl32swap(w1, w3);
        pl32swap(w4, w6);
        pl32swap(w5, w7);
        int4 p0v, p1v;
        p0v.x = (int)w0; p0v.y = (int)w1; p0v.z = (int)w2; p0v.w = (int)w3;
        p1v.x = (int)w4; p1v.y = (int)w5; p1v.z = (int)w6; p1v.w = (int)w7;
        bf16x8 pb0 = __builtin_bit_cast(bf16x8, p0v);
        bf16x8 pb1 = __builtin_bit_cast(bf16x8, p1v);
        o0 = __builtin_amdgcn_mfma_f32_32x32x16_bf16(vf[0][0], pb0, o0, 0, 0, 0);
        o0 = __builtin_amdgcn_mfma_f32_32x32x16_bf16(vf[0][1], pb1, o0, 0, 0, 0);
        o1 = __builtin_amdgcn_mfma_f32_32x32x16_bf16(vf[1][0], pb0, o1, 0, 0, 0);
        o1 = __builtin_amdgcn_mfma_f32_32x32x16_bf16(vf[1][1], pb1, o1, 0, 0, 0);
        if (kc < 63) {
            *(uint4*)&Kt[buf ^ 1][kr][kq * 8] = knx;
            *(uint4*)&Vt[buf ^ 1][vd][vp * 8] = vnx;
        }
        __syncthreads();
    }
    float lrun = (ls.x + ls.y) + (ls.z + ls.w);
    lrun += __shfl_xor(lrun, 32);
    // partial writes: fp32, no normalization (merge kernel does o/(l0+l1))
    float* pp = Po + ((size_t)(kh * 16 + bh_i) * 4096 + q0 + l31) * 64 + 4 * l5;
#pragma unroll
    for (int g = 0; g < 4; ++g) {
        *(float4*)&pp[8 * g] =
            make_float4(o0[4 * g + 0], o0[4 * g + 1], o0[4 * g + 2], o0[4 * g + 3]);
        *(float4*)&pp[32 + 8 * g] =
            make_float4(o1[4 * g + 0], o1[4 * g + 1], o1[4 * g + 2], o1[4 * g + 3]);
    }
    if (l5 == 0) Pl[(size_t)(kh * 16 + bh_i) * 4096 + q0 + l31] = lrun;
}

// ---------------- Merge k-split partials: aoT[b][q][h*64+d] = (Po0+Po1)/(l0+l1) ----------------
__global__ __launch_bounds__(256) void attn_merge_kernel(
        const float* __restrict__ Po,   // [2][16][4096][64]
        const float* __restrict__ Pl,   // [2][16][4096]
        unsigned short* __restrict__ aoT) {
    const int t = threadIdx.x;
    const int ri = blockIdx.x * 64 + (t >> 2);      // bh*4096 + q, 0..65535
    const int d0 = (t & 3) * 16;
    const int bh = ri >> 12, q = ri & 4095;
    const int b = bh >> 2, h = bh & 3;
    const float l0 = Pl[ri], l1 = Pl[65536 + ri];
    const float inv = 1.f / (l0 + l1);
    const float* p0 = Po + (size_t)ri * 64 + d0;
    const float* p1 = p0 + (size_t)65536 * 64;
    unsigned short* op = aoT + ((size_t)b * L + q) * 256 + h * 64 + d0;
#pragma unroll
    for (int g = 0; g < 2; ++g) {
        float4 a0 = *(const float4*)&p0[g * 8 + 0];
        float4 a1 = *(const float4*)&p0[g * 8 + 4];
        float4 c0 = *(const float4*)&p1[g * 8 + 0];
        float4 c1 = *(const float4*)&p1[g * 8 + 4];
        uint4 st;
        st.x = cvtpk((a0.x + c0.x) * inv, (a0.y + c0.y) * inv);
        st.y = cvtpk((a0.z + c0.z) * inv, (a0.w + c0.w) * inv);
        st.z = cvtpk((a1.x + c1.x) * inv, (a1.y + c1.y) * inv);
        st.w = cvtpk((a1.z + c1.z) * inv, (a1.w + c1.w) * inv);
        *(uint4*)&op[g * 8] = st;
    }
}

// ---------------- Proj GEMM (MFMA) + bias + GN residual, fp32 out ----------------
__global__ __launch_bounds__(256) void proj_gemm_kernel(
        const unsigned short* __restrict__ aoT,
        const unsigned short* __restrict__ Wp,
        const float* __restrict__ bias,
        const float* __restrict__ x,
        const float* __restrict__ gamma,
        const float* __restrict__ beta,
        const float2* __restrict__ stats,
        float* __restrict__ out) {
    const int t = threadIdx.x, lane = t & 63, w = t >> 6;
    const int l5 = lane >> 5, l31 = lane & 31;
    const int wn = w & 1, wm = w >> 1;
    const int n0 = blockIdx.x * 64 + wn * 32;
    const int m0 = blockIdx.y * 128 + wm * 64;
    const int b = blockIdx.z;
    const unsigned short* ap = aoT + ((size_t)b * L + n0 + l31) * 256 + l5 * 8;
    const unsigned short* bp = Wp + (size_t)(m0 + l31) * 256 + l5 * 8;
    f32x16 acc[2];
#pragma unroll
    for (int j = 0; j < 2; ++j)
#pragma unroll
        for (int r = 0; r < 16; ++r) acc[j][r] = 0.f;
#pragma unroll
    for (int k0 = 0; k0 < 256; k0 += 16) {
        bf16x8 a  = ld_frag_g(ap + k0);
        bf16x8 b0 = ld_frag_g(bp + k0);
        bf16x8 b1 = ld_frag_g(bp + 32 * 256 + k0);
        acc[0] = __builtin_amdgcn_mfma_f32_32x32x16_bf16(a, b0, acc[0], 0, 0, 0);
        acc[1] = __builtin_amdgcn_mfma_f32_32x32x16_bf16(a, b1, acc[1], 0, 0, 0);
    }
#pragma unroll
    for (int j = 0; j < 2; ++j) {
        const int co = m0 + j * 32 + l31;
        const float2 st = stats[b * 8 + (co >> 5)];
        const float g = gamma[co] * st.y;
        const float be = beta[co] - st.x * g + bias[co];
        const float* xr = &x[((size_t)b * 256 + co) * L];
        float* orow = &out[((size_t)b * 256 + co) * L];
#pragma unroll
        for (int q = 0; q < 4; ++q) {
            const int n = n0 + 8 * q + 4 * l5;
            float4 xv = *(const float4*)&xr[n];
            float4 ov;
            ov.x = acc[j][4 * q + 0] + (xv.x * g + be);
            ov.y = acc[j][4 * q + 1] + (xv.y * g + be);
            ov.z = acc[j][4 * q + 2] + (xv.z * g + be);
            ov.w = acc[j][4 * q + 3] + (xv.w * g + be);
            *(float4*)&orow[n] = ov;
        }
    }
}

extern "C" void kernel_launch(void* const* d_in, const int* in_sizes, int n_in,
                              void* d_out, int out_size, void* d_ws, size_t ws_size,
                              hipStream_t stream) {
    const float* x      = (const float*)d_in[0];
    const float* qkv_w  = (const float*)d_in[1];
    const float* qkv_b  = (const float*)d_in[2];
    const float* proj_w = (const float*)d_in[3];
    const float* proj_b = (const float*)d_in[4];
    const float* gamma  = (const float*)d_in[5];
    const float* beta   = (const float*)d_in[6];
    float* out = (float*)d_out;

    char* ws = (char*)d_ws;
    float2* stats       = (float2*)ws;                                   // 256 B
    unsigned short* Wqb = (unsigned short*)(ws + 512);                   // 384 KiB
    unsigned short* Wpb = (unsigned short*)(ws + 512 + 393216);          // 128 KiB
    unsigned short* xnT = (unsigned short*)(ws + 524800);                // 8 MiB
    unsigned short* Qb  = (unsigned short*)(ws + 524800 + 8388608);      // 8 MiB
    unsigned short* Kb  = Qb + (size_t)16 * L * 64;                      // 8 MiB
    unsigned short* Vb  = Kb + (size_t)16 * L * 64;                      // 8 MiB
    unsigned short* aoT = Vb + (size_t)16 * L * 64;                      // 8 MiB
    float* Po           = (float*)(ws + 42467840);                       // 32 MiB (k-split partials)
    float* Pl           = (float*)(ws + 42467840 + 33554432);            // 512 KiB
    // stats partials live at the head of the xnT region: consumed by gn_stats_final
    // BEFORE gn_apply writes xnT (stream-ordered) — no extra workspace needed.
    float2* spart       = (float2*)(ws + 524800);                        // 4 KiB

    gn_stats_part_kernel<<<dim3(512), dim3(256), 0, stream>>>(x, spart);
    gn_stats_final_kernel<<<dim3(1), dim3(64), 0, stream>>>(spart, stats);
    wcvt_kernel<<<dim3(256), dim3(256), 0, stream>>>(qkv_w, proj_w, Wqb, Wpb);
    gn_apply_kernel<<<dim3(64, 4, 4), dim3(256), 0, stream>>>(x, gamma, beta, stats, xnT);
    qkv_gemm_kernel<<<dim3(32, 6, 4), dim3(256), 0, stream>>>(xnT, Wqb, qkv_b, Qb, Kb, Vb);
    attn_kernel<<<dim3(1024), dim3(256), 0, stream>>>(Qb, Kb, Vb, Po, Pl);
    attn_merge_kernel<<<dim3(1024), dim3(256), 0, stream>>>(Po, Pl, aoT);
    proj_gemm_kernel<<<dim3(64, 2, 4), dim3(256), 0, stream>>>(aoT, Wpb, proj_b, x, gamma, beta, stats, out);
}